// Round 1
// baseline (407.273 us; speedup 1.0000x reference)
//
#include <hip/hip_runtime.h>

typedef __bf16 bf16_t;
typedef bf16_t bf16x8 __attribute__((ext_vector_type(8)));
typedef float f32x4 __attribute__((ext_vector_type(4)));
typedef unsigned short u16;
typedef unsigned int u32;

static constexpr int kHW = 192 * 320;   // 61440
static constexpr int kS  = 264;         // act row stride in u16 (256 + 8 pad, keeps 16B align)

// round-to-nearest-even f32 -> bf16 (values are finite; no NaN handling needed)
__device__ __forceinline__ u16 f2bf(float f) {
  u32 u = __float_as_uint(f);
  return (u16)((u + 0x7FFFu + ((u >> 16) & 1u)) >> 16);
}

// bf16 weight workspace layout (element offsets)
static constexpr int OFF_W0 = 0;        // [64][64]   (cols 0..63 of w0; t-column folded into bias)
static constexpr int OFF_W1 = 4096;     // [64][64]
static constexpr int OFF_W2 = 8192;     // [256][64]
static constexpr int OFF_W3 = 24576;    // [256][256]
static constexpr int OFF_W4 = 90112;    // [256][256]
static constexpr int OFF_W5 = 155648;   // [64][256]
static constexpr int W_TOTAL = 172032;  // 344,064 bytes

__global__ void convert_weights(const float* __restrict__ w0, const float* __restrict__ w1,
                                const float* __restrict__ w2, const float* __restrict__ w3,
                                const float* __restrict__ w4, const float* __restrict__ w5,
                                u16* __restrict__ wb) {
  int i = blockIdx.x * 256 + threadIdx.x;
  float v;
  if (i < OFF_W1)      { int o = i >> 6, k = i & 63; v = w0[o * 65 + k]; }
  else if (i < OFF_W2) { v = w1[i - OFF_W1]; }
  else if (i < OFF_W3) { v = w2[i - OFF_W2]; }
  else if (i < OFF_W4) { v = w3[i - OFF_W3]; }
  else if (i < OFF_W5) { v = w4[i - OFF_W4]; }
  else                 { v = w5[i - OFF_W5]; }
  wb[i] = f2bf(v);
}

// One layer: D[o][p] = sum_k W[o][k] * act[p][k]  (+ bias), tile 16x16x32 MFMA.
// A-operand = weights (held in VGPRs, read from global bf16, L2-hot),
// B-operand = activations (ds_read_b128 from LDS), waves partition o.
template<int K, int N, bool LAST>
__device__ __forceinline__ void layer_fn(const u16* __restrict__ wb,
                                         const float* bias_lds,
                                         const u16* act_in, u16* act_out,
                                         float* __restrict__ out_base) {
  constexpr int KT = K / 32;   // k-steps
  constexpr int OT = N / 64;   // o-tiles per wave
  const int tid  = threadIdx.x;
  const int lane = tid & 63;
  const int wave = tid >> 6;
  const int l15  = lane & 15;
  const int quad = lane >> 4;

  // A-frags: lane holds W[o = base + (lane&15)][k = ks*32 + quad*8 + j], 16B contiguous
  bf16x8 wf[OT][KT];
#pragma unroll
  for (int ot = 0; ot < OT; ++ot) {
    const int o = (wave * OT + ot) * 16 + l15;
#pragma unroll
    for (int ks = 0; ks < KT; ++ks)
      wf[ot][ks] = *reinterpret_cast<const bf16x8*>(wb + o * K + ks * 32 + quad * 8);
  }
  // bias: D rows are o = tile*16 + quad*4 + r  -> float4 per o-tile
  f32x4 bv[OT];
#pragma unroll
  for (int ot = 0; ot < OT; ++ot)
    bv[ot] = *reinterpret_cast<const f32x4*>(bias_lds + (wave * OT + ot) * 16 + quad * 4);

#pragma unroll
  for (int pt = 0; pt < 4; ++pt) {
    // B-frags: lane holds act[p = pt*16 + (lane&15)][k = ks*32 + quad*8 + j]
    bf16x8 af[KT];
#pragma unroll
    for (int ks = 0; ks < KT; ++ks)
      af[ks] = *reinterpret_cast<const bf16x8*>(act_in + (pt * 16 + l15) * kS + ks * 32 + quad * 8);

    f32x4 acc[OT];
#pragma unroll
    for (int ot = 0; ot < OT; ++ot) acc[ot] = bv[ot];
#pragma unroll
    for (int ks = 0; ks < KT; ++ks)
#pragma unroll
      for (int ot = 0; ot < OT; ++ot)
        acc[ot] = __builtin_amdgcn_mfma_f32_16x16x32_bf16(wf[ot][ks], af[ks], acc[ot], 0, 0, 0);

    const int p = pt * 16 + l15;
#pragma unroll
    for (int ot = 0; ot < OT; ++ot) {
      if constexpr (LAST) {
        const int o = (wave * OT + ot) * 16 + quad * 4;
        float* dst = out_base + (size_t)o * kHW + p;
#pragma unroll
        for (int r = 0; r < 4; ++r) dst[(size_t)r * kHW] = acc[ot][r];
      } else {
        u16 h0 = f2bf(__sinf(30.0f * acc[ot][0]));
        u16 h1 = f2bf(__sinf(30.0f * acc[ot][1]));
        u16 h2 = f2bf(__sinf(30.0f * acc[ot][2]));
        u16 h3 = f2bf(__sinf(30.0f * acc[ot][3]));
        uint2 v;
        v.x = (u32)h0 | ((u32)h1 << 16);
        v.y = (u32)h2 | ((u32)h3 << 16);
        // 4 consecutive o for fixed p -> one aligned 8B write
        *reinterpret_cast<uint2*>(act_out + p * kS + (wave * OT + ot) * 16 + quad * 4) = v;
      }
    }
  }
}

__global__ void __launch_bounds__(256, 2)
siren_main(const float* __restrict__ feat, const float* __restrict__ times,
           const float* __restrict__ w0f,
           const float* __restrict__ b0, const float* __restrict__ b1,
           const float* __restrict__ b2, const float* __restrict__ b3,
           const float* __restrict__ b4, const float* __restrict__ b5,
           const u16* __restrict__ wb, float* __restrict__ out) {
  __shared__ __align__(16) u16 actA[64 * kS];
  __shared__ __align__(16) u16 actB[64 * kS];
  __shared__ __align__(16) float bias_lds[960];

  const int tid = threadIdx.x;
  const int bid = blockIdx.x;
  const int c   = bid / 1920;       // time index
  const int pb  = bid % 1920;
  const int p0  = pb * 64;          // global point within this time (0..122879)
  const int bq  = p0 / kHW;         // batch index (64 | kHW so no straddle)
  const int hw0 = p0 % kHW;

  const float t = times[c];

  // stage biases (fp32); fold t * W0[:,64] into layer-0 bias
  if (tid < 64) {
    bias_lds[tid]       = b0[tid] + t * w0f[tid * 65 + 64];
    bias_lds[64 + tid]  = b1[tid];
    bias_lds[896 + tid] = b5[tid];
  }
  bias_lds[128 + tid] = b2[tid];
  bias_lds[384 + tid] = b3[tid];
  bias_lds[640 + tid] = b4[tid];

  // stage input: act[p][ch] = bf16(feat[bq][ch][hw0+p])  (gather is identity)
  {
    const float* fbase = feat + (size_t)bq * 64 * kHW + hw0;
#pragma unroll
    for (int it = 0; it < 16; ++it) {
      int ch = it * 4 + (tid >> 6);
      int p  = tid & 63;
      actA[p * kS + ch] = f2bf(fbase[(size_t)ch * kHW + p]);
    }
  }
  __syncthreads();

  float* out_base = out + (size_t)(c * 2 + bq) * 64 * kHW + hw0;

  layer_fn<64, 64, false>(wb + OFF_W0, bias_lds + 0, actA, actB, nullptr);
  __syncthreads();
  layer_fn<64, 64, false>(wb + OFF_W1, bias_lds + 64, actB, actA, nullptr);
  __syncthreads();
  layer_fn<64, 256, false>(wb + OFF_W2, bias_lds + 128, actA, actB, nullptr);
  __syncthreads();
  layer_fn<256, 256, false>(wb + OFF_W3, bias_lds + 384, actB, actA, nullptr);
  __syncthreads();
  layer_fn<256, 256, false>(wb + OFF_W4, bias_lds + 640, actA, actB, nullptr);
  __syncthreads();
  layer_fn<256, 64, true>(wb + OFF_W5, bias_lds + 896, actB, actA, out_base);
}

extern "C" void kernel_launch(void* const* d_in, const int* in_sizes, int n_in,
                              void* d_out, int out_size, void* d_ws, size_t ws_size,
                              hipStream_t stream) {
  const float* feat  = (const float*)d_in[0];
  const float* times = (const float*)d_in[1];
  const float* w0 = (const float*)d_in[2];
  const float* b0 = (const float*)d_in[3];
  const float* w1 = (const float*)d_in[4];
  const float* b1 = (const float*)d_in[5];
  const float* w2 = (const float*)d_in[6];
  const float* b2 = (const float*)d_in[7];
  const float* w3 = (const float*)d_in[8];
  const float* b3 = (const float*)d_in[9];
  const float* w4 = (const float*)d_in[10];
  const float* b4 = (const float*)d_in[11];
  const float* w5 = (const float*)d_in[12];
  const float* b5 = (const float*)d_in[13];
  u16* wb = (u16*)d_ws;
  float* out = (float*)d_out;

  convert_weights<<<W_TOTAL / 256, 256, 0, stream>>>(w0, w1, w2, w3, w4, w5, wb);
  siren_main<<<5760, 256, 0, stream>>>(feat, times, w0, b0, b1, b2, b3, b4, b5, wb, out);
}

// Round 2
// 403.086 us; speedup vs baseline: 1.0104x; 1.0104x over previous
//
#include <hip/hip_runtime.h>
#include <hip/hip_bf16.h>

typedef __bf16 bf16_t;
typedef bf16_t bf16x8 __attribute__((ext_vector_type(8)));
typedef float f32x4 __attribute__((ext_vector_type(4)));
typedef unsigned short u16;
typedef unsigned int u32;

static constexpr int kHW = 192 * 320;          // 61440
static constexpr float kC = 4.77464829275686f; // 30 / (2*pi)

// round-to-nearest-even f32 -> bf16
__device__ __forceinline__ u16 f2bf(float f) {
  u32 u = __float_as_uint(f);
  return (u16)((u + 0x7FFFu + ((u >> 16) & 1u)) >> 16);
}

__device__ __forceinline__ u32 pack2(float a, float b) {
  __hip_bfloat162 h = __float22bfloat162_rn(make_float2(a, b));
  union { __hip_bfloat162 h2; u32 u; } cv;
  cv.h2 = h;
  return cv.u;
}

// bf16 weight workspace layout (element offsets). W0..W4 pre-scaled by kC.
static constexpr int OFF_W0 = 0;        // [64][64] (t-column folded into bias)
static constexpr int OFF_W1 = 4096;     // [64][64]
static constexpr int OFF_W2 = 8192;     // [256][64]
static constexpr int OFF_W3 = 24576;    // [256][256]
static constexpr int OFF_W4 = 90112;    // [256][256]
static constexpr int OFF_W5 = 155648;   // [64][256] (NOT scaled)
static constexpr int W_TOTAL = 172032;  // u16 elements
// fp32 bias block appended after weights (float offsets within bws):
// cb0[64]@0, cw64[64]@64, cb1[64]@128, cb2[256]@192, cb3[256]@448,
// cb4[256]@704, b5[64]@960   -> 1024 floats. cb*/cw64 pre-scaled by kC.
static constexpr int B_TOTAL = 1024;

__global__ void convert_weights(const float* __restrict__ w0, const float* __restrict__ w1,
                                const float* __restrict__ w2, const float* __restrict__ w3,
                                const float* __restrict__ w4, const float* __restrict__ w5,
                                const float* __restrict__ b0, const float* __restrict__ b1,
                                const float* __restrict__ b2, const float* __restrict__ b3,
                                const float* __restrict__ b4, const float* __restrict__ b5,
                                u16* __restrict__ wb, float* __restrict__ bws) {
  int i = blockIdx.x * 256 + threadIdx.x;
  if (i < W_TOTAL) {
    float v, s = kC;
    if (i < OFF_W1)      { int o = i >> 6, k = i & 63; v = w0[o * 65 + k]; }
    else if (i < OFF_W2) { v = w1[i - OFF_W1]; }
    else if (i < OFF_W3) { v = w2[i - OFF_W2]; }
    else if (i < OFF_W4) { v = w3[i - OFF_W3]; }
    else if (i < OFF_W5) { v = w4[i - OFF_W4]; }
    else                 { v = w5[i - OFF_W5]; s = 1.0f; }
    wb[i] = f2bf(v * s);
  } else {
    int j = i - W_TOTAL;  // 0..1023
    float v;
    if (j < 64)       v = kC * b0[j];
    else if (j < 128) v = kC * w0[(j - 64) * 65 + 64];
    else if (j < 192) v = kC * b1[j - 128];
    else if (j < 448) v = kC * b2[j - 192];
    else if (j < 704) v = kC * b3[j - 448];
    else if (j < 960) v = kC * b4[j - 704];
    else              v = b5[j - 960];
    bws[j] = v;
  }
}

// One layer: D[o][p] = sum_k W[o][k]*act[p][k] + bias.
// Weights (A-operand) in VGPRs from global (L2-hot); activations (B-operand)
// from XOR-swizzled LDS (granule g -> g ^ (row&7), row stride 256 u16).
template<int K, int NOT, int NPT, bool LAST>
__device__ __forceinline__ void layer_fn(const u16* __restrict__ wb, const float* bias,
                                         const u16* act_in, u16* act_out,
                                         float* __restrict__ out_base,
                                         int o_tile0, int pt0, int lane) {
  constexpr int KT = K / 32;
  const int l15  = lane & 15;
  const int quad = lane >> 4;
  const int sw   = l15 & 7;

  bf16x8 wf[NOT][KT];
  f32x4  bv[NOT];
#pragma unroll
  for (int ot = 0; ot < NOT; ++ot) {
    const int o = (o_tile0 + ot) * 16 + l15;
#pragma unroll
    for (int ks = 0; ks < KT; ++ks)
      wf[ot][ks] = *reinterpret_cast<const bf16x8*>(wb + o * K + ks * 32 + quad * 8);
    bv[ot] = *reinterpret_cast<const f32x4*>(bias + (o_tile0 + ot) * 16 + quad * 4);
  }

#pragma unroll 1
  for (int ip = 0; ip < NPT; ++ip) {
    const int p = (pt0 + ip) * 16 + l15;
    bf16x8 af[KT];
#pragma unroll
    for (int ks = 0; ks < KT; ++ks)
      af[ks] = *reinterpret_cast<const bf16x8*>(act_in + p * 256 + (((ks * 4 + quad) ^ sw) * 8));

#pragma unroll
    for (int ot = 0; ot < NOT; ++ot) {
      f32x4 acc = bv[ot];
#pragma unroll
      for (int ks = 0; ks < KT; ++ks)
        acc = __builtin_amdgcn_mfma_f32_16x16x32_bf16(wf[ot][ks], af[ks], acc, 0, 0, 0);

      if constexpr (LAST) {
        const int o = (o_tile0 + ot) * 16 + quad * 4;
        float* dst = out_base + (size_t)o * kHW + p;
#pragma unroll
        for (int r = 0; r < 4; ++r) dst[(size_t)r * kHW] = acc[r];
      } else {
        // act = sin(2*pi*frac(acc)) = sin(30*(Wh+b))  [weights pre-scaled]
        float s0 = __builtin_amdgcn_sinf(__builtin_amdgcn_fractf(acc[0]));
        float s1 = __builtin_amdgcn_sinf(__builtin_amdgcn_fractf(acc[1]));
        float s2 = __builtin_amdgcn_sinf(__builtin_amdgcn_fractf(acc[2]));
        float s3 = __builtin_amdgcn_sinf(__builtin_amdgcn_fractf(acc[3]));
        uint2 v;
        v.x = pack2(s0, s1);
        v.y = pack2(s2, s3);
        const int g = (o_tile0 + ot) * 2 + (quad >> 1);  // 16B-granule of col0
        *reinterpret_cast<uint2*>(act_out + p * 256 + ((g ^ sw) * 8) + (quad & 1) * 4) = v;
      }
    }
  }
}

__global__ void __launch_bounds__(512, 4)
siren_main(const float* __restrict__ feat, const float* __restrict__ times,
           const u16* __restrict__ wb, const float* __restrict__ bws,
           float* __restrict__ out) {
  __shared__ __align__(16) u16 actA[64 * 256];
  __shared__ __align__(16) u16 actB[64 * 256];
  __shared__ __align__(16) float bias_lds[960];

  const int tid = threadIdx.x;
  const int bid = blockIdx.x;
  const int c   = bid / 1920;
  const int pb  = bid % 1920;
  const int p0  = pb * 64;
  const int bq  = p0 / kHW;
  const int hw0 = p0 % kHW;
  const float t = times[c];

  // bias staging: [0,64) = c*(b0 + t*w0col64); [64,960) = straight copy
  if (tid < 64) bias_lds[tid] = bws[tid] + t * bws[64 + tid];
  for (int i = tid; i < 896; i += 512) bias_lds[64 + i] = bws[128 + i];

  // input staging: act[p][ch] = bf16(feat[bq][ch][hw0+p]), swizzled, one b128/thread
  {
    const float* fbase = feat + (size_t)bq * 64 * kHW + hw0;
    const int p = tid & 63;
    const int g = tid >> 6;  // channel granule 0..7
    float v[8];
#pragma unroll
    for (int j = 0; j < 8; ++j) v[j] = fbase[(size_t)(g * 8 + j) * kHW + p];
    uint4 pk;
    pk.x = pack2(v[0], v[1]);
    pk.y = pack2(v[2], v[3]);
    pk.z = pack2(v[4], v[5]);
    pk.w = pack2(v[6], v[7]);
    *reinterpret_cast<uint4*>(actA + p * 256 + ((g ^ (p & 7)) * 8)) = pk;
  }
  __syncthreads();

  const int wave = tid >> 6;
  const int lane = tid & 63;
  float* out_base = out + (size_t)(c * 2 + bq) * 64 * kHW + hw0;

  // N=64 layers: 8 waves = 4 o-tiles x 2 pt-pairs; N=256 layers: 8 waves x 2 o-tiles
  const int ot64  = wave & 3;
  const int pt64  = (wave >> 2) * 2;
  const int ot256 = wave * 2;

  layer_fn<64, 1, 2, false>(wb + OFF_W0, bias_lds + 0,   actA, actB, nullptr, ot64, pt64, lane);
  __syncthreads();
  layer_fn<64, 1, 2, false>(wb + OFF_W1, bias_lds + 64,  actB, actA, nullptr, ot64, pt64, lane);
  __syncthreads();
  layer_fn<64, 2, 4, false>(wb + OFF_W2, bias_lds + 128, actA, actB, nullptr, ot256, 0, lane);
  __syncthreads();
  layer_fn<256, 2, 4, false>(wb + OFF_W3, bias_lds + 384, actB, actA, nullptr, ot256, 0, lane);
  __syncthreads();
  layer_fn<256, 2, 4, false>(wb + OFF_W4, bias_lds + 640, actA, actB, nullptr, ot256, 0, lane);
  __syncthreads();
  layer_fn<256, 1, 2, true >(wb + OFF_W5, bias_lds + 896, actB, nullptr, out_base, ot64, pt64, lane);
}

extern "C" void kernel_launch(void* const* d_in, const int* in_sizes, int n_in,
                              void* d_out, int out_size, void* d_ws, size_t ws_size,
                              hipStream_t stream) {
  const float* feat  = (const float*)d_in[0];
  const float* times = (const float*)d_in[1];
  const float* w0 = (const float*)d_in[2];
  const float* b0 = (const float*)d_in[3];
  const float* w1 = (const float*)d_in[4];
  const float* b1 = (const float*)d_in[5];
  const float* w2 = (const float*)d_in[6];
  const float* b2 = (const float*)d_in[7];
  const float* w3 = (const float*)d_in[8];
  const float* b3 = (const float*)d_in[9];
  const float* w4 = (const float*)d_in[10];
  const float* b4 = (const float*)d_in[11];
  const float* w5 = (const float*)d_in[12];
  const float* b5 = (const float*)d_in[13];
  u16*   wb  = (u16*)d_ws;
  float* bws = (float*)((char*)d_ws + (size_t)W_TOTAL * 2);
  float* out = (float*)d_out;

  convert_weights<<<(W_TOTAL + B_TOTAL) / 256, 256, 0, stream>>>(
      w0, w1, w2, w3, w4, w5, b0, b1, b2, b3, b4, b5, wb, bws);
  siren_main<<<5760, 512, 0, stream>>>(feat, times, wb, bws, out);
}